// Round 2
// baseline (1614.647 us; speedup 1.0000x reference)
//
#include <hip/hip_runtime.h>

// CorrVolume1DBlock: cv[n,i,h,w] = (1/C) * sum_c x1[n,c,h,w] * x2[n,c,h,w-i],
// zero where w-i < 0.  B=8, C=128, H=128, W=256, i in [0,64], fp32.
//
// R2: conflict-free LDS mapping. One block per (n,h); 256 threads = 4 waves.
// Lane l (tid&63) owns w in [4l,4l+4); wave q (tid>>6) owns i in [16q,16q+16).
// Every ds_read_b128 has lane-stride exactly 16 B (lane L -> chunk L), the
// conflict-free pattern. Per c-step/thread: 1 b128 (x1) + 5 b128 (x2 window,
// 20 floats feed all 64 FMAs via x2r[wl-il+16]). KC=16 -> 36 KB LDS ->
// 4 blocks/CU (grid 1024 = exactly 4 x 256 CUs co-resident).

constexpr int B   = 8;
constexpr int C   = 128;
constexpr int H   = 128;
constexpr int W   = 256;
constexpr int NI  = 65;             // disparity slices 0..64
constexpr int HW  = H * W;          // 32768
constexpr int CHW = C * HW;         // 4194304
constexpr int KC  = 16;             // c-chunk staged in LDS
constexpr int X2W = 320;            // x2 tile cols: j in [0,320) <-> w' = j-64

__global__ __launch_bounds__(256, 4)
void corr_volume_kernel(const float* __restrict__ x1,
                        const float* __restrict__ x2,
                        float* __restrict__ out) {
    const int h   = blockIdx.x;
    const int n   = blockIdx.y;
    const int tid = threadIdx.x;
    const int l   = tid & 63;   // lane: w-group of 4 -> w = 4l..4l+3
    const int q   = tid >> 6;   // wave: i-group of 16 -> i = 16q..16q+15

    __shared__ __align__(16) float x1s[KC][W];    // 16 KB
    __shared__ __align__(16) float x2s[KC][X2W];  // 20 KB

    float acc[16][4];
    #pragma unroll
    for (int il = 0; il < 16; ++il)
        #pragma unroll
        for (int wl = 0; wl < 4; ++wl) acc[il][wl] = 0.0f;
    float acc64[4] = {0.f, 0.f, 0.f, 0.f};  // i == 64, live for wave 0 only

    // x2 window this thread needs: j = w - i + 64 in [4l-16q+49, 4l-16q+67]
    // -> read 20 floats from aligned j0 (index used: wl - il + 16 in [1,19]).
    const int j0 = 4 * l - 16 * q + 48;   // in [0, 300], 16B-aligned

    const float* x1g = x1 + n * CHW + h * W;
    const float* x2g = x2 + n * CHW + h * W;

    // Zero-fill x2s left margin (j < 64 <-> w' < 0) ONCE; rows are reused
    // across c-chunks and this region is never overwritten.
    {
        // KC*16 = 256 float4 pad entries; one per thread.
        const int row = tid >> 4;
        const int col = tid & 15;
        ((float4*)(&x2s[row][0]))[col] = make_float4(0.f, 0.f, 0.f, 0.f);
    }

    for (int c0 = 0; c0 < C; c0 += KC) {
        // ---- stage x1: KC rows x 64 float4, flat contiguous ----
        #pragma unroll
        for (int k = 0; k < (KC * (W / 4)) / 256; ++k) {
            const int e   = tid + k * 256;
            const int row = e >> 6;
            const int col = e & 63;
            ((float4*)x1s)[e] =
                *(const float4*)(x1g + (c0 + row) * HW + col * 4);
        }
        // ---- stage x2: KC rows x 64 float4 into cols [64,320) ----
        #pragma unroll
        for (int k = 0; k < (KC * (W / 4)) / 256; ++k) {
            const int e    = tid + k * 256;
            const int row  = e >> 6;
            const int colq = e & 63;
            *(float4*)(&x2s[row][64 + colq * 4]) =
                *(const float4*)(x2g + (c0 + row) * HW + colq * 4);
        }
        __syncthreads();

        for (int c = 0; c < KC; ++c) {
            const float4 a = *(const float4*)&x1s[c][l * 4];
            const float x1r[4] = {a.x, a.y, a.z, a.w};
            const float4* p2 = (const float4*)&x2s[c][j0];
            const float4 b0 = p2[0], b1 = p2[1], b2 = p2[2],
                         b3 = p2[3], b4 = p2[4];
            const float x2r[20] = {b0.x, b0.y, b0.z, b0.w,
                                   b1.x, b1.y, b1.z, b1.w,
                                   b2.x, b2.y, b2.z, b2.w,
                                   b3.x, b3.y, b3.z, b3.w,
                                   b4.x, b4.y, b4.z, b4.w};
            #pragma unroll
            for (int il = 0; il < 16; ++il)
                #pragma unroll
                for (int wl = 0; wl < 4; ++wl)
                    acc[il][wl] = fmaf(x1r[wl], x2r[wl - il + 16], acc[il][wl]);

            if (q == 0) {  // i == 64: w' = w-64 lives at LDS col j = w = 4l
                const float4 d = *(const float4*)&x2s[c][l * 4];
                #pragma unroll
                for (int wl = 0; wl < 4; ++wl)
                    acc64[wl] = fmaf(x1r[wl], d.x * 0.f + ((const float*)&d)[wl],
                                     acc64[wl]);
            }
        }
        __syncthreads();
    }

    // ---- epilogue: out[n, i, h, w], lane-contiguous float4 stores ----
    const float scale = 1.0f / (float)C;
    float* outg = out + n * (NI * HW) + h * W + l * 4;
    #pragma unroll
    for (int il = 0; il < 16; ++il) {
        const int i = q * 16 + il;
        *(float4*)(outg + i * HW) =
            make_float4(acc[il][0] * scale, acc[il][1] * scale,
                        acc[il][2] * scale, acc[il][3] * scale);
    }
    if (q == 0) {
        *(float4*)(outg + 64 * HW) =
            make_float4(acc64[0] * scale, acc64[1] * scale,
                        acc64[2] * scale, acc64[3] * scale);
    }
}

extern "C" void kernel_launch(void* const* d_in, const int* in_sizes, int n_in,
                              void* d_out, int out_size, void* d_ws, size_t ws_size,
                              hipStream_t stream) {
    const float* x1 = (const float*)d_in[0];
    const float* x2 = (const float*)d_in[1];
    float* out = (float*)d_out;
    dim3 grid(H, B);   // 1024 blocks, one per (n, h); 4 blocks/CU co-resident
    corr_volume_kernel<<<grid, 256, 0, stream>>>(x1, x2, out);
}

// Round 3
// 1049.315 us; speedup vs baseline: 1.5388x; 1.5388x over previous
//
#include <hip/hip_runtime.h>

// CorrVolume1DBlock: cv[n,i,h,w] = (1/C) * sum_c x1[n,c,h,w] * x2[n,c,h,w-i],
// zero where w-i < 0.  B=8, C=128, H=128, W=256, i in [0,64], fp32.
//
// R3 = R2's conflict-free LDS mapping + R1's register budget.
// One block per (n,h); 256 threads = 4 waves. Lane l (tid&63) owns
// w in [4l,4l+4); wave q (tid>>6) owns i in [16q,16q+16). Every
// ds_read_b128 has lane-stride exactly 16 B -> conflict-free by
// construction. Per c-step/thread: 1 b128 (x1) + 5 b128 (x2 window; 20
// floats feed 64 FMAs via x2r[wl-il+16]). KC=16 -> 36 KB LDS -> 4 blocks/CU.
//
// __launch_bounds__(256,2): R2's (256,4) made the compiler clamp to 64 VGPRs
// and spill the 64-float accumulator to scratch (5.1 GB HBM traffic, 1424us).
// (256,2) caps at 256; compiler lands ~100-120, 4 waves/SIMD, no spill.

constexpr int B   = 8;
constexpr int C   = 128;
constexpr int H   = 128;
constexpr int W   = 256;
constexpr int NI  = 65;             // disparity slices 0..64
constexpr int HW  = H * W;          // 32768
constexpr int CHW = C * HW;         // 4194304
constexpr int KC  = 16;             // c-chunk staged in LDS
constexpr int X2W = 320;            // x2 tile cols: j in [0,320) <-> w' = j-64

__global__ __launch_bounds__(256, 2)
void corr_volume_kernel(const float* __restrict__ x1,
                        const float* __restrict__ x2,
                        float* __restrict__ out) {
    const int h   = blockIdx.x;
    const int n   = blockIdx.y;
    const int tid = threadIdx.x;
    const int l   = tid & 63;   // lane: w-group of 4 -> w = 4l..4l+3
    const int q   = tid >> 6;   // wave: i-group of 16 -> i = 16q..16q+15

    __shared__ __align__(16) float x1s[KC][W];    // 16 KB
    __shared__ __align__(16) float x2s[KC][X2W];  // 20 KB

    float acc[16][4];
    #pragma unroll
    for (int il = 0; il < 16; ++il)
        #pragma unroll
        for (int wl = 0; wl < 4; ++wl) acc[il][wl] = 0.0f;
    float acc64[4] = {0.f, 0.f, 0.f, 0.f};  // i == 64, live for wave 0 only

    // x2 window this thread needs: j = w - i + 64 = j0 + (wl - il + 16),
    // wl-il+16 in [1,19] -> 20-float aligned window at j0.
    const int j0 = 4 * l - 16 * q + 48;   // in [0, 300], 16B-aligned

    const float* x1g = x1 + n * CHW + h * W;
    const float* x2g = x2 + n * CHW + h * W;

    // Zero-fill x2s left margin (j < 64 <-> w' < 0) ONCE; never overwritten.
    {
        const int row = tid >> 4;   // [0,16)
        const int col = tid & 15;   // [0,16) float4s -> floats 0..63
        ((float4*)(&x2s[row][0]))[col] = make_float4(0.f, 0.f, 0.f, 0.f);
    }

    for (int c0 = 0; c0 < C; c0 += KC) {
        // ---- stage x1: KC rows x 64 float4, flat contiguous ----
        #pragma unroll
        for (int k = 0; k < (KC * (W / 4)) / 256; ++k) {
            const int e   = tid + k * 256;
            const int row = e >> 6;
            const int col = e & 63;
            ((float4*)x1s)[e] =
                *(const float4*)(x1g + (c0 + row) * HW + col * 4);
        }
        // ---- stage x2: KC rows x 64 float4 into cols [64,320) ----
        #pragma unroll
        for (int k = 0; k < (KC * (W / 4)) / 256; ++k) {
            const int e    = tid + k * 256;
            const int row  = e >> 6;
            const int colq = e & 63;
            *(float4*)(&x2s[row][64 + colq * 4]) =
                *(const float4*)(x2g + (c0 + row) * HW + colq * 4);
        }
        __syncthreads();

        for (int c = 0; c < KC; ++c) {
            const float4 a = *(const float4*)&x1s[c][l * 4];
            const float x1r[4] = {a.x, a.y, a.z, a.w};
            const float4* p2 = (const float4*)&x2s[c][j0];
            const float4 b0 = p2[0], b1 = p2[1], b2 = p2[2],
                         b3 = p2[3], b4 = p2[4];
            const float x2r[20] = {b0.x, b0.y, b0.z, b0.w,
                                   b1.x, b1.y, b1.z, b1.w,
                                   b2.x, b2.y, b2.z, b2.w,
                                   b3.x, b3.y, b3.z, b3.w,
                                   b4.x, b4.y, b4.z, b4.w};
            #pragma unroll
            for (int il = 0; il < 16; ++il)
                #pragma unroll
                for (int wl = 0; wl < 4; ++wl)
                    acc[il][wl] = fmaf(x1r[wl], x2r[wl - il + 16], acc[il][wl]);

            if (q == 0) {  // i == 64: w' = w-64 lives at LDS col j = w = 4l
                const float4 d = *(const float4*)&x2s[c][l * 4];
                const float x2c[4] = {d.x, d.y, d.z, d.w};
                #pragma unroll
                for (int wl = 0; wl < 4; ++wl)
                    acc64[wl] = fmaf(x1r[wl], x2c[wl], acc64[wl]);
            }
        }
        __syncthreads();
    }

    // ---- epilogue: out[n, i, h, w], lane-contiguous float4 stores ----
    const float scale = 1.0f / (float)C;
    float* outg = out + n * (NI * HW) + h * W + l * 4;
    #pragma unroll
    for (int il = 0; il < 16; ++il) {
        const int i = q * 16 + il;
        *(float4*)(outg + i * HW) =
            make_float4(acc[il][0] * scale, acc[il][1] * scale,
                        acc[il][2] * scale, acc[il][3] * scale);
    }
    if (q == 0) {
        *(float4*)(outg + 64 * HW) =
            make_float4(acc64[0] * scale, acc64[1] * scale,
                        acc64[2] * scale, acc64[3] * scale);
    }
}

extern "C" void kernel_launch(void* const* d_in, const int* in_sizes, int n_in,
                              void* d_out, int out_size, void* d_ws, size_t ws_size,
                              hipStream_t stream) {
    const float* x1 = (const float*)d_in[0];
    const float* x2 = (const float*)d_in[1];
    float* out = (float*)d_out;
    dim3 grid(H, B);   // 1024 blocks, one per (n, h)
    corr_volume_kernel<<<grid, 256, 0, stream>>>(x1, x2, out);
}

// Round 4
// 318.018 us; speedup vs baseline: 5.0772x; 3.2996x over previous
//
#include <hip/hip_runtime.h>
#include <hip/hip_fp16.h>

// CorrVolume1DBlock: cv[n,i,h,w] = (1/C) * sum_c x1[n,c,h,w] * x2[n,c,h,w-i],
// zero where w-i < 0.  B=8, C=128, H=128, W=256, i in [0,64], fp32 in/out.
//
// R4: f16-pair dot-product formulation to structurally kill the register
// pressure that made R2/R3 spill (VGPR allocator chose 64/128 and dumped the
// 64-float accumulator to scratch -> GBs of HBM traffic).
//  - Inputs converted fp32->fp16 (RTN) during staging; channel pairs packed
//    into half2. v_dot2_f32_f16 (f32 accumulate) does 2 MACs/instr.
//  - 512 threads = 8 waves per block, one block per (n,h).
//    lane l = tid&63 owns w in [4l,4l+4); wave q = tid>>6 owns i in [8q,8q+8)
//    (wave 0 also does i=64).  acc[8][4] = 32 regs; x2 window 12 regs;
//    ~60 live VGPRs -> no spill under the 128 cap of __launch_bounds__(512,4).
//  - All LDS reads/writes are b128 with exact 16 B lane stride: conflict-free.
//  - Precision: rel err 2^-11 per input, f32 accumulate -> absmax ~2e-3
//    vs 9.96e-3 threshold.

constexpr int B   = 8;
constexpr int C   = 128;
constexpr int H   = 128;
constexpr int W   = 256;
constexpr int NI  = 65;
constexpr int HW  = H * W;
constexpr int CHW = C * HW;
constexpr int KC2 = 16;            // c-PAIRS per chunk (32 channels), 4 chunks
constexpr int X2W = 320;           // x2 cols: j in [0,320) <-> w' = j-64

typedef _Float16 half2v __attribute__((ext_vector_type(2)));

__device__ inline unsigned int pack2(float a, float b) {
    __half2 h = __floats2half2_rn(a, b);     // a -> low, b -> high
    return __builtin_bit_cast(unsigned int, h);
}

__device__ inline float fdot2f(unsigned int a, unsigned int b, float c) {
#if __has_builtin(__builtin_amdgcn_fdot2)
    return __builtin_amdgcn_fdot2(__builtin_bit_cast(half2v, a),
                                  __builtin_bit_cast(half2v, b), c, false);
#else
    __half2 ha = __builtin_bit_cast(__half2, a);
    __half2 hb = __builtin_bit_cast(__half2, b);
    float2 fa = __half22float2(ha), fb = __half22float2(hb);
    return fmaf(fa.x, fb.x, fmaf(fa.y, fb.y, c));
#endif
}

__global__ __launch_bounds__(512, 4)
void corr_volume_kernel(const float* __restrict__ x1,
                        const float* __restrict__ x2,
                        float* __restrict__ out) {
    const int h   = blockIdx.x;
    const int n   = blockIdx.y;
    const int tid = threadIdx.x;
    const int l   = tid & 63;   // w = 4l .. 4l+3
    const int q   = tid >> 6;   // i = 8q .. 8q+7 (wave q); q==0 also i=64

    __shared__ unsigned int x1h[KC2][W];    // 16 KB, half2 over (2c2, 2c2+1)
    __shared__ unsigned int x2h[KC2][X2W];  // 20 KB, cols [0,64) = zero margin

    float acc[8][4];
    #pragma unroll
    for (int il = 0; il < 8; ++il)
        #pragma unroll
        for (int wl = 0; wl < 4; ++wl) acc[il][wl] = 0.0f;
    float acc64[4] = {0.f, 0.f, 0.f, 0.f};

    // x2 window: LDS col j = w - i + 64 = j0 + (wl - il + 8), wl-il+8 in [1,11]
    const int j0 = 4 * l - 8 * q + 56;   // in [0, 308], uint4-aligned

    const float* x1g = x1 + n * CHW + h * W;
    const float* x2g = x2 + n * CHW + h * W;

    // Zero-fill x2h's left margin once (rows reused every chunk, never overwritten).
    if (tid < 256) {
        const int r  = tid >> 4;    // [0,16)
        const int cq = tid & 15;    // 16 uint4 per row covers cols [0,64)
        *(uint4*)&x2h[r][4 * cq] = make_uint4(0u, 0u, 0u, 0u);
    }

    for (int c0 = 0; c0 < C; c0 += 2 * KC2) {
        // ---- stage + convert: each e handles one w-quad of one c-pair row ----
        #pragma unroll
        for (int k = 0; k < 2; ++k) {
            const int e  = tid + k * 512;   // [0, 1024)
            const int r  = e >> 6;          // c-pair row [0,16)
            const int cq = e & 63;          // w-quad [0,64)
            {
                const float4 lo = *(const float4*)(x1g + (c0 + 2 * r) * HW + 4 * cq);
                const float4 hi = *(const float4*)(x1g + (c0 + 2 * r + 1) * HW + 4 * cq);
                uint4 p;
                p.x = pack2(lo.x, hi.x); p.y = pack2(lo.y, hi.y);
                p.z = pack2(lo.z, hi.z); p.w = pack2(lo.w, hi.w);
                *(uint4*)&x1h[r][4 * cq] = p;
            }
            {
                const float4 lo = *(const float4*)(x2g + (c0 + 2 * r) * HW + 4 * cq);
                const float4 hi = *(const float4*)(x2g + (c0 + 2 * r + 1) * HW + 4 * cq);
                uint4 p;
                p.x = pack2(lo.x, hi.x); p.y = pack2(lo.y, hi.y);
                p.z = pack2(lo.z, hi.z); p.w = pack2(lo.w, hi.w);
                *(uint4*)&x2h[r][64 + 4 * cq] = p;
            }
        }
        __syncthreads();

        #pragma unroll 2
        for (int c2 = 0; c2 < KC2; ++c2) {
            const uint4 a4 = *(const uint4*)&x1h[c2][4 * l];
            const unsigned int aw[4] = {a4.x, a4.y, a4.z, a4.w};
            const uint4 b0 = *(const uint4*)&x2h[c2][j0];
            const uint4 b1 = *(const uint4*)&x2h[c2][j0 + 4];
            const uint4 b2 = *(const uint4*)&x2h[c2][j0 + 8];
            const unsigned int bw[12] = {b0.x, b0.y, b0.z, b0.w,
                                         b1.x, b1.y, b1.z, b1.w,
                                         b2.x, b2.y, b2.z, b2.w};
            #pragma unroll
            for (int il = 0; il < 8; ++il)
                #pragma unroll
                for (int wl = 0; wl < 4; ++wl)
                    acc[il][wl] = fdot2f(aw[wl], bw[wl - il + 8], acc[il][wl]);

            if (q == 0) {  // i == 64: w' = w-64 lives at LDS col j = w = 4l
                const uint4 d = *(const uint4*)&x2h[c2][4 * l];
                const unsigned int dw[4] = {d.x, d.y, d.z, d.w};
                #pragma unroll
                for (int wl = 0; wl < 4; ++wl)
                    acc64[wl] = fdot2f(aw[wl], dw[wl], acc64[wl]);
            }
        }
        __syncthreads();
    }

    // ---- epilogue: out[n, i, h, w], lane-contiguous float4 stores ----
    const float scale = 1.0f / (float)C;
    float* outg = out + n * (NI * HW) + h * W + 4 * l;
    #pragma unroll
    for (int il = 0; il < 8; ++il) {
        const int i = 8 * q + il;
        *(float4*)(outg + i * HW) =
            make_float4(acc[il][0] * scale, acc[il][1] * scale,
                        acc[il][2] * scale, acc[il][3] * scale);
    }
    if (q == 0) {
        *(float4*)(outg + 64 * HW) =
            make_float4(acc64[0] * scale, acc64[1] * scale,
                        acc64[2] * scale, acc64[3] * scale);
    }
}

extern "C" void kernel_launch(void* const* d_in, const int* in_sizes, int n_in,
                              void* d_out, int out_size, void* d_ws, size_t ws_size,
                              hipStream_t stream) {
    const float* x1 = (const float*)d_in[0];
    const float* x2 = (const float*)d_in[1];
    float* out = (float*)d_out;
    dim3 grid(H, B);   // 1024 blocks, one per (n, h)
    corr_volume_kernel<<<grid, 512, 0, stream>>>(x1, x2, out);
}